// Round 3
// baseline (1317.171 us; speedup 1.0000x reference)
//
#include <hip/hip_runtime.h>
#include <stdint.h>

// W4A16 grouped-quant linear on MI355X.
// Harness promotes the reference's fp16 tensors to FLOAT32 (only bf16 stays
// 16-bit), so: x f32[4096,4096], qweight i32[11008,2048] (2 nibbles/int32),
// scale f32[11008,32], zero i32[11008,32], bias f32[11008], out f32[4096,11008].
// out[m][n] = sum_k x[m,k] * (nib(qw[n,k/2],k&1) - z[n,k/128]) * s[n,k/128] + bias[n]
#define MDIM 4096
#define NDIM 11008
#define KDIM 4096
#define KHALF 2048  // int32 per qweight row
#define NGRP 32     // groups of 128 along K
#define BM 128
#define BN 128
#define BK 64
#define NTH 256
#define NTILN (NDIM / BN)          // 86
#define NWG ((MDIM / BM) * NTILN)  // 2752, divisible by 8
#define NXCD 8

typedef __attribute__((ext_vector_type(4))) float f32x4;
typedef __attribute__((ext_vector_type(8))) _Float16 f16x8;
typedef __attribute__((ext_vector_type(4))) int i32x4;
typedef __attribute__((ext_vector_type(4))) unsigned int u32x4;

__device__ __forceinline__ unsigned int pk16(float a, float b) {
  // v_cvt_pkrtz_f16_f32: a -> low half, b -> high half. RTZ.
  return __builtin_bit_cast(unsigned int, __builtin_amdgcn_cvt_pkrtz(a, b));
}
// Dequant 2 nibbles of one int32 -> packed 2x f16 (k-even in low half).
// f = 2^23|nib, fz = 2^23|z are exact; (f - fz) is Sterbenz-exact; only the
// multiply by s and the RTZ-to-f16 round (rel err <= ~2^-10 total).
__device__ __forceinline__ unsigned int dq_pair(int qi, float fz, float s) {
  unsigned int q = (unsigned int)qi;
  float f0 = __uint_as_float((q & 0xFu) | 0x4B000000u);
  float f1 = __uint_as_float(((q >> 4) & 0xFu) | 0x4B000000u);
  return pk16((f0 - fz) * s, (f1 - fz) * s);
}

__global__ void __launch_bounds__(NTH)
wlinear_w4a16(const float* __restrict__ x,
              const int* __restrict__ qw,
              const float* __restrict__ scl,
              const int* __restrict__ zro,
              const float* __restrict__ bia,
              float* __restrict__ outp)
{
  // Chunk-swizzled tiles: row r, logical 8-half chunk c stored at physical
  // slot c ^ (r & 7). Same involution on write and read (both reg-staged).
  __shared__ _Float16 ldsA[BM][BK]; // 16 KB
  __shared__ _Float16 ldsB[BN][BK]; // 16 KB

  const int tid = threadIdx.x;
  // bijective XCD swizzle (NWG % 8 == 0); consecutive orig ids share an
  // A-panel (same by), so each XCD keeps its A-panel L2-resident.
  int wg = blockIdx.x;
  wg = (wg & (NXCD - 1)) * (NWG / NXCD) + (wg >> 3);
  const int by = wg / NTILN;
  const int bx = wg - by * NTILN;
  const int m0 = by * BM;
  const int n0 = bx * BN;

  // ---- staging mapping: 2 threads per tile row; thread covers 32 k-values
  const int srow = tid >> 1;  // 0..127 (row within both A and B tiles)
  const int sh = tid & 1;     // which 32-wide k-half of the BK=64 step
  const int ssw = srow & 7;
  const float* xrow = x + (size_t)(m0 + srow) * KDIM + sh * 32;
  const int* qrow = qw + (size_t)(n0 + srow) * KHALF + sh * 16;
  const float* sclrow = scl + (size_t)(n0 + srow) * NGRP;
  const int* zrow = zro + (size_t)(n0 + srow) * NGRP;

  // ---- wave / fragment decomposition (2x2 waves, 64x64 per wave)
  const int wave = tid >> 6;
  const int lane = tid & 63;
  const int wr = wave >> 1;
  const int wc = wave & 1;
  const int fr = lane & 15;
  const int fq = lane >> 4;
  const int off0 = ((fq ^ (fr & 7)) << 3); // half-offset of k-chunk 0..3

  const f32x4 fzero = {0.f, 0.f, 0.f, 0.f};
  f32x4 acc[4][4];
#pragma unroll
  for (int i = 0; i < 4; ++i)
#pragma unroll
    for (int j = 0; j < 4; ++j) acc[i][j] = fzero;

  // prologue: prefetch step-0 operands into registers
  f32x4 xv[8];
  i32x4 qv[4];
  {
    const f32x4* xp = (const f32x4*)xrow;
#pragma unroll
    for (int i = 0; i < 8; ++i) xv[i] = xp[i];
    const i32x4* qp = (const i32x4*)qrow;
#pragma unroll
    for (int i = 0; i < 4; ++i) qv[i] = qp[i];
  }
  float s_n = sclrow[0];
  float fz_n = __uint_as_float(0x4B000000u | (unsigned int)zrow[0]);

  for (int k0 = 0; k0 < KDIM; k0 += BK) {
    __syncthreads(); // previous compute done: safe to overwrite LDS

    // A tile: f32 regs -> f16, swizzled ds_write_b128 (exact cvt: x was fp16)
#pragma unroll
    for (int j = 0; j < 4; ++j) {
      u32x4 wch;
      wch[0] = pk16(xv[2 * j][0], xv[2 * j][1]);
      wch[1] = pk16(xv[2 * j][2], xv[2 * j][3]);
      wch[2] = pk16(xv[2 * j + 1][0], xv[2 * j + 1][1]);
      wch[3] = pk16(xv[2 * j + 1][2], xv[2 * j + 1][3]);
      const int ps = (sh * 4 + j) ^ ssw;
      *(u32x4*)&ldsA[srow][ps << 3] = wch;
    }
    // B tile: dequant int32 regs -> f16, swizzled ds_write_b128
#pragma unroll
    for (int ii = 0; ii < 4; ++ii) {
      u32x4 wch;
#pragma unroll
      for (int e = 0; e < 4; ++e) wch[e] = dq_pair(qv[ii][e], fz_n, s_n);
      const int ps = (sh * 4 + ii) ^ ssw;
      *(u32x4*)&ldsB[srow][ps << 3] = wch;
    }

    // prefetch next step's operands (latency overlaps the ds_writes above)
    if (k0 + BK < KDIM) {
      const f32x4* xp = (const f32x4*)(xrow + k0 + BK);
#pragma unroll
      for (int i = 0; i < 8; ++i) xv[i] = xp[i];
      const i32x4* qp = (const i32x4*)(qrow + ((k0 + BK) >> 1));
#pragma unroll
      for (int i = 0; i < 4; ++i) qv[i] = qp[i];
      const int gn = (k0 + BK) >> 7;
      s_n = sclrow[gn];
      fz_n = __uint_as_float(0x4B000000u | (unsigned int)zrow[gn]);
    }

    __syncthreads(); // staging visible

#pragma unroll
    for (int ks = 0; ks < BK; ks += 32) {
      const int off = (ks == 0) ? off0 : (off0 ^ 32);
      f16x8 a[4], b[4];
#pragma unroll
      for (int mi = 0; mi < 4; ++mi)
        a[mi] = *(const f16x8*)&ldsA[wr * 64 + mi * 16 + fr][off];
#pragma unroll
      for (int ni = 0; ni < 4; ++ni)
        b[ni] = *(const f16x8*)&ldsB[wc * 64 + ni * 16 + fr][off];
#pragma unroll
      for (int mi = 0; mi < 4; ++mi)
#pragma unroll
        for (int ni = 0; ni < 4; ++ni)
          acc[mi][ni] = __builtin_amdgcn_mfma_f32_16x16x32_f16(
              a[mi], b[ni], acc[mi][ni], 0, 0, 0);
    }
  }

  // epilogue: C/D layout col(n) = lane&15, row(m) = (lane>>4)*4 + reg
#pragma unroll
  for (int ni = 0; ni < 4; ++ni) {
    const int n = n0 + wc * 64 + ni * 16 + fr;
    const float bv = bia[n];
#pragma unroll
    for (int mi = 0; mi < 4; ++mi) {
      const int m = m0 + wr * 64 + mi * 16 + (fq << 2);
      const size_t base = (size_t)m * NDIM + n;
#pragma unroll
      for (int j = 0; j < 4; ++j)
        outp[base + (size_t)j * NDIM] = acc[mi][ni][j] + bv;
    }
  }
}

extern "C" void kernel_launch(void* const* d_in, const int* in_sizes, int n_in,
                              void* d_out, int out_size, void* d_ws, size_t ws_size,
                              hipStream_t stream) {
  (void)in_sizes; (void)n_in; (void)out_size; (void)d_ws; (void)ws_size;
  const float* x = (const float*)d_in[0];
  const int* qw = (const int*)d_in[1];
  const float* scl = (const float*)d_in[2];
  const int* zro = (const int*)d_in[3];
  const float* bia = (const float*)d_in[4];
  float* outp = (float*)d_out;

  dim3 grid(NWG), block(NTH);
  wlinear_w4a16<<<grid, block, 0, stream>>>(x, qw, scl, zro, bia, outp);
}

// Round 5
// 730.339 us; speedup vs baseline: 1.8035x; 1.8035x over previous
//
#include <hip/hip_runtime.h>
#include <stdint.h>

// W4A16 grouped-quant linear on MI355X (harness promotes fp16 -> f32):
// x f32[4096,4096], qweight i32[11008,2048] (2 nibbles per int32),
// scale f32[11008,32], zero i32[11008,32], bias f32[11008], out f32[4096,11008].
//
// Round 4 (resubmit; round-4 bench was a broker timeout): two-pass. Prep
// dequantizes W -> fp16 and converts x -> fp16 into d_ws; GEMM then uses
// global_load_lds(16B) staging for both operands (m97 structure). Fallback
// to the round-3 fused kernel if ws is too small.
#define MDIM 4096
#define NDIM 11008
#define KDIM 4096
#define KHALF 2048
#define NGRP 32
#define BM 128
#define BN 128
#define BK 64
#define NTH 256
#define NTILN (NDIM / BN)          // 86
#define NWG ((MDIM / BM) * NTILN)  // 2752, divisible by 8
#define NXCD 8

#define WBYTES ((size_t)NDIM * KDIM * 2)        // 90,177,536
#define XBYTES ((size_t)MDIM * KDIM * 2)        // 33,554,432
#define WS_NEED (WBYTES + XBYTES)

typedef __attribute__((ext_vector_type(4))) float f32x4;
typedef __attribute__((ext_vector_type(8))) _Float16 f16x8;
typedef __attribute__((ext_vector_type(4))) int i32x4;
typedef __attribute__((ext_vector_type(4))) unsigned int u32x4;

__device__ __forceinline__ unsigned int pk16(float a, float b) {
  // v_cvt_pkrtz_f16_f32: a -> low half, b -> high half.
  return __builtin_bit_cast(unsigned int, __builtin_amdgcn_cvt_pkrtz(a, b));
}
// Dequant 2 nibbles of one int32 -> packed 2x f16 (k-even in low half).
// f = 2^23|nib, fz = 2^23|z are exact; (f-fz) is Sterbenz-exact.
__device__ __forceinline__ unsigned int dq_pair(int qi, float fz, float s) {
  unsigned int q = (unsigned int)qi;
  float f0 = __uint_as_float((q & 0xFu) | 0x4B000000u);
  float f1 = __uint_as_float(((q >> 4) & 0xFu) | 0x4B000000u);
  return pk16((f0 - fz) * s, (f1 - fz) * s);
}
__device__ __forceinline__ void load_lds16(const void* g, void* l) {
  __builtin_amdgcn_global_load_lds(
      (__attribute__((address_space(1))) void*)(void*)g,
      (__attribute__((address_space(3))) void*)l, 16, 0, 0);
}

// ---------------- prep pass 1: W4 -> fp16 [N][K] ----------------
__global__ void __launch_bounds__(256)
dequant_w(const int* __restrict__ qw, const float* __restrict__ scl,
          const int* __restrict__ zro, _Float16* __restrict__ wh) {
  const unsigned int QTOT = (unsigned int)NDIM * KHALF;  // 22,544,384
  const unsigned int stride = gridDim.x * blockDim.x;
  for (unsigned int t = blockIdx.x * blockDim.x + threadIdx.x; t * 4u < QTOT;
       t += stride) {
    const unsigned int f = t * 4u;          // int32 index (16B aligned)
    const unsigned int n = f >> 11;         // / KHALF
    const unsigned int kk = f & (KHALF - 1);
    const unsigned int g = kk >> 6;         // 64 int32 per 128-group
    const float s = scl[n * NGRP + g];
    const float fz = __uint_as_float(0x4B000000u | (unsigned int)zro[n * NGRP + g]);
    const i32x4 q = *(const i32x4*)(qw + f);
    u32x4 w;
#pragma unroll
    for (int e = 0; e < 4; ++e) w[e] = dq_pair(q[e], fz, s);
    *(u32x4*)(wh + (size_t)f * 2) = w;
  }
}

// ---------------- prep pass 2: x f32 -> fp16 (exact) ----------------
__global__ void __launch_bounds__(256)
cvt_x(const float* __restrict__ x, _Float16* __restrict__ xh) {
  const unsigned int XTOT = (unsigned int)MDIM * KDIM;  // 16,777,216
  const unsigned int stride = gridDim.x * blockDim.x;
  for (unsigned int t = blockIdx.x * blockDim.x + threadIdx.x; t * 8u < XTOT;
       t += stride) {
    const unsigned int f = t * 8u;
    const f32x4 a = *(const f32x4*)(x + f);
    const f32x4 b = *(const f32x4*)(x + f + 4);
    u32x4 w;
    w[0] = pk16(a[0], a[1]);
    w[1] = pk16(a[2], a[3]);
    w[2] = pk16(b[0], b[1]);
    w[3] = pk16(b[2], b[3]);
    *(u32x4*)(xh + f) = w;
  }
}

// ---------------- pass 3: fp16 GEMM, global_load_lds staging ----------------
// LDS layout per tile row (64 fp16 = 8 chunks of 16B): logical chunk cl is
// stored at physical chunk cl ^ (row & 7). gload_lds dest is LINEAR; the
// swizzle is folded into the per-lane GLOBAL source column (rule #21).
__global__ void __launch_bounds__(NTH)
gemm_f16(const _Float16* __restrict__ xh, const _Float16* __restrict__ wh,
         const float* __restrict__ bia, float* __restrict__ outp) {
  __shared__ _Float16 ldsA[BM * BK];  // 16 KB
  __shared__ _Float16 ldsB[BN * BK];  // 16 KB

  const int tid = threadIdx.x;
  int wg = blockIdx.x;  // bijective XCD swizzle (NWG % 8 == 0)
  wg = (wg & (NXCD - 1)) * (NWG / NXCD) + (wg >> 3);
  const int by = wg / NTILN;
  const int bx = wg - by * NTILN;
  const int m0 = by * BM;
  const int n0 = bx * BN;

  // staging: 1024 chunks of 16B per tile; 4 per thread
  const _Float16* asrc[4];
  const _Float16* bsrc[4];
  _Float16* adst[4];
  _Float16* bdst[4];
#pragma unroll
  for (int i = 0; i < 4; ++i) {
    const int c = i * NTH + tid;
    const int row = c >> 3;
    const int col = ((c & 7) ^ (row & 7)) << 3;  // pre-swizzled source col
    asrc[i] = xh + (size_t)(m0 + row) * KDIM + col;
    bsrc[i] = wh + (size_t)(n0 + row) * KDIM + col;
    adst[i] = &ldsA[c * 8];
    bdst[i] = &ldsB[c * 8];
  }

  // wave / fragment decomposition (2x2 waves, 64x64 per wave)
  const int wave = tid >> 6;
  const int lane = tid & 63;
  const int wr = wave >> 1;
  const int wc = wave & 1;
  const int fr = lane & 15;
  const int fq = lane >> 4;
  const int off0 = (fq ^ (fr & 7)) << 3;  // physical fp16 offset of k-chunk

  const f32x4 fzero = {0.f, 0.f, 0.f, 0.f};
  f32x4 acc[4][4];
#pragma unroll
  for (int i = 0; i < 4; ++i)
#pragma unroll
    for (int j = 0; j < 4; ++j) acc[i][j] = fzero;

  for (int k0 = 0; k0 < KDIM; k0 += BK) {
    __syncthreads();  // previous compute done
#pragma unroll
    for (int i = 0; i < 4; ++i) load_lds16(asrc[i] + k0, adst[i]);
#pragma unroll
    for (int i = 0; i < 4; ++i) load_lds16(bsrc[i] + k0, bdst[i]);
    __syncthreads();  // compiler drains vmcnt before barrier

#pragma unroll
    for (int ks = 0; ks < BK; ks += 32) {
      const int off = (ks == 0) ? off0 : (off0 ^ 32);
      f16x8 a[4], b[4];
#pragma unroll
      for (int mi = 0; mi < 4; ++mi)
        a[mi] = *(const f16x8*)&ldsA[(wr * 64 + mi * 16 + fr) * BK + off];
#pragma unroll
      for (int ni = 0; ni < 4; ++ni)
        b[ni] = *(const f16x8*)&ldsB[(wc * 64 + ni * 16 + fr) * BK + off];
#pragma unroll
      for (int mi = 0; mi < 4; ++mi)
#pragma unroll
        for (int ni = 0; ni < 4; ++ni)
          acc[mi][ni] = __builtin_amdgcn_mfma_f32_16x16x32_f16(
              a[mi], b[ni], acc[mi][ni], 0, 0, 0);
    }
  }

  // epilogue: C/D layout col(n) = lane&15, row(m) = (lane>>4)*4 + reg
#pragma unroll
  for (int ni = 0; ni < 4; ++ni) {
    const int n = n0 + wc * 64 + ni * 16 + fr;
    const float bv = bia[n];
#pragma unroll
    for (int mi = 0; mi < 4; ++mi) {
      const int m = m0 + wr * 64 + mi * 16 + (fq << 2);
      const size_t base = (size_t)m * NDIM + n;
#pragma unroll
      for (int j = 0; j < 4; ++j)
        outp[base + (size_t)j * NDIM] = acc[mi][ni][j] + bv;
    }
  }
}

// ---------------- fallback: round-3 fused kernel (passes, 1170 us) --------
__global__ void __launch_bounds__(NTH)
wlinear_fused(const float* __restrict__ x, const int* __restrict__ qw,
              const float* __restrict__ scl, const int* __restrict__ zro,
              const float* __restrict__ bia, float* __restrict__ outp) {
  __shared__ _Float16 ldsA[BM][BK];
  __shared__ _Float16 ldsB[BN][BK];

  const int tid = threadIdx.x;
  int wg = blockIdx.x;
  wg = (wg & (NXCD - 1)) * (NWG / NXCD) + (wg >> 3);
  const int by = wg / NTILN;
  const int bx = wg - by * NTILN;
  const int m0 = by * BM;
  const int n0 = bx * BN;

  const int srow = tid >> 1;
  const int sh = tid & 1;
  const int ssw = srow & 7;
  const float* xrow = x + (size_t)(m0 + srow) * KDIM + sh * 32;
  const int* qrow = qw + (size_t)(n0 + srow) * KHALF + sh * 16;
  const float* sclrow = scl + (size_t)(n0 + srow) * NGRP;
  const int* zrow = zro + (size_t)(n0 + srow) * NGRP;

  const int wave = tid >> 6;
  const int lane = tid & 63;
  const int wr = wave >> 1;
  const int wc = wave & 1;
  const int fr = lane & 15;
  const int fq = lane >> 4;
  const int off0 = ((fq ^ (fr & 7)) << 3);

  const f32x4 fzero = {0.f, 0.f, 0.f, 0.f};
  f32x4 acc[4][4];
#pragma unroll
  for (int i = 0; i < 4; ++i)
#pragma unroll
    for (int j = 0; j < 4; ++j) acc[i][j] = fzero;

  f32x4 xv[8];
  i32x4 qv[4];
  {
    const f32x4* xp = (const f32x4*)xrow;
#pragma unroll
    for (int i = 0; i < 8; ++i) xv[i] = xp[i];
    const i32x4* qp = (const i32x4*)qrow;
#pragma unroll
    for (int i = 0; i < 4; ++i) qv[i] = qp[i];
  }
  float s_n = sclrow[0];
  float fz_n = __uint_as_float(0x4B000000u | (unsigned int)zrow[0]);

  for (int k0 = 0; k0 < KDIM; k0 += BK) {
    __syncthreads();
#pragma unroll
    for (int j = 0; j < 4; ++j) {
      u32x4 wch;
      wch[0] = pk16(xv[2 * j][0], xv[2 * j][1]);
      wch[1] = pk16(xv[2 * j][2], xv[2 * j][3]);
      wch[2] = pk16(xv[2 * j + 1][0], xv[2 * j + 1][1]);
      wch[3] = pk16(xv[2 * j + 1][2], xv[2 * j + 1][3]);
      const int ps = (sh * 4 + j) ^ ssw;
      *(u32x4*)&ldsA[srow][ps << 3] = wch;
    }
#pragma unroll
    for (int ii = 0; ii < 4; ++ii) {
      u32x4 wch;
#pragma unroll
      for (int e = 0; e < 4; ++e) wch[e] = dq_pair(qv[ii][e], fz_n, s_n);
      const int ps = (sh * 4 + ii) ^ ssw;
      *(u32x4*)&ldsB[srow][ps << 3] = wch;
    }
    if (k0 + BK < KDIM) {
      const f32x4* xp = (const f32x4*)(xrow + k0 + BK);
#pragma unroll
      for (int i = 0; i < 8; ++i) xv[i] = xp[i];
      const i32x4* qp = (const i32x4*)(qrow + ((k0 + BK) >> 1));
#pragma unroll
      for (int i = 0; i < 4; ++i) qv[i] = qp[i];
      const int gn = (k0 + BK) >> 7;
      s_n = sclrow[gn];
      fz_n = __uint_as_float(0x4B000000u | (unsigned int)zrow[gn]);
    }
    __syncthreads();

#pragma unroll
    for (int ks = 0; ks < BK; ks += 32) {
      const int off = (ks == 0) ? off0 : (off0 ^ 32);
      f16x8 a[4], b[4];
#pragma unroll
      for (int mi = 0; mi < 4; ++mi)
        a[mi] = *(const f16x8*)&ldsA[wr * 64 + mi * 16 + fr][off];
#pragma unroll
      for (int ni = 0; ni < 4; ++ni)
        b[ni] = *(const f16x8*)&ldsB[wc * 64 + ni * 16 + fr][off];
#pragma unroll
      for (int mi = 0; mi < 4; ++mi)
#pragma unroll
        for (int ni = 0; ni < 4; ++ni)
          acc[mi][ni] = __builtin_amdgcn_mfma_f32_16x16x32_f16(
              a[mi], b[ni], acc[mi][ni], 0, 0, 0);
    }
  }

#pragma unroll
  for (int ni = 0; ni < 4; ++ni) {
    const int n = n0 + wc * 64 + ni * 16 + fr;
    const float bv = bia[n];
#pragma unroll
    for (int mi = 0; mi < 4; ++mi) {
      const int m = m0 + wr * 64 + mi * 16 + (fq << 2);
      const size_t base = (size_t)m * NDIM + n;
#pragma unroll
      for (int j = 0; j < 4; ++j)
        outp[base + (size_t)j * NDIM] = acc[mi][ni][j] + bv;
    }
  }
}

extern "C" void kernel_launch(void* const* d_in, const int* in_sizes, int n_in,
                              void* d_out, int out_size, void* d_ws, size_t ws_size,
                              hipStream_t stream) {
  (void)in_sizes; (void)n_in; (void)out_size;
  const float* x = (const float*)d_in[0];
  const int* qw = (const int*)d_in[1];
  const float* scl = (const float*)d_in[2];
  const int* zro = (const int*)d_in[3];
  const float* bia = (const float*)d_in[4];
  float* outp = (float*)d_out;

  if (ws_size >= WS_NEED) {
    _Float16* wh = (_Float16*)d_ws;
    _Float16* xh = (_Float16*)((char*)d_ws + WBYTES);
    dequant_w<<<2048, 256, 0, stream>>>(qw, scl, zro, wh);
    cvt_x<<<1024, 256, 0, stream>>>(x, xh);
    gemm_f16<<<NWG, NTH, 0, stream>>>(xh, wh, bia, outp);
  } else {
    wlinear_fused<<<NWG, NTH, 0, stream>>>(x, qw, scl, zro, bia, outp);
  }
}

// Round 6
// 618.388 us; speedup vs baseline: 2.1300x; 1.1810x over previous
//
#include <hip/hip_runtime.h>
#include <stdint.h>

// W4A16 grouped-quant linear on MI355X (harness promotes fp16 -> f32):
// x f32[4096,4096], qweight i32[11008,2048] (2 nibbles per int32),
// scale f32[11008,32], zero i32[11008,32], bias f32[11008], out f32[4096,11008].
//
// Round 6: prep passes (dequant W->fp16, cvt x->fp16 into d_ws) unchanged;
// GEMM upgraded from m97 2-barrier structure (772 TF measured) to the 256^2
// 8-phase schedule (T1 XCD-swizzle + T2 LDS swizzle + T3/T4 counted vmcnt +
// T5 setprio). Fallback to round-3 fused kernel if ws too small.
#define MDIM 4096
#define NDIM 11008
#define KDIM 4096
#define KHALF 2048
#define NGRP 32
#define NXCD 8

#define WBYTES ((size_t)NDIM * KDIM * 2)  // 90,177,536
#define XBYTES ((size_t)MDIM * KDIM * 2)  // 33,554,432
#define WS_NEED (WBYTES + XBYTES)

// 8-phase GEMM geometry
#define G_BM 256
#define G_BN 256
#define G_BK 64
#define G_NTH 512
#define G_NTILN (NDIM / G_BN)             // 43
#define G_NWG ((MDIM / G_BM) * G_NTILN)   // 688, divisible by 8

// fallback geometry (round-3 kernel)
#define F_BM 128
#define F_BN 128
#define F_BK 64
#define F_NTH 256
#define F_NTILN (NDIM / F_BN)             // 86
#define F_NWG ((MDIM / F_BM) * F_NTILN)   // 2752

typedef __attribute__((ext_vector_type(4))) float f32x4;
typedef __attribute__((ext_vector_type(8))) _Float16 f16x8;
typedef __attribute__((ext_vector_type(4))) int i32x4;
typedef __attribute__((ext_vector_type(4))) unsigned int u32x4;

__device__ __forceinline__ unsigned int pk16(float a, float b) {
  return __builtin_bit_cast(unsigned int, __builtin_amdgcn_cvt_pkrtz(a, b));
}
__device__ __forceinline__ unsigned int dq_pair(int qi, float fz, float s) {
  unsigned int q = (unsigned int)qi;
  float f0 = __uint_as_float((q & 0xFu) | 0x4B000000u);
  float f1 = __uint_as_float(((q >> 4) & 0xFu) | 0x4B000000u);
  return pk16((f0 - fz) * s, (f1 - fz) * s);
}
__device__ __forceinline__ void load_lds16(const void* g, void* l) {
  __builtin_amdgcn_global_load_lds(
      (__attribute__((address_space(1))) void*)(void*)g,
      (__attribute__((address_space(3))) void*)l, 16, 0, 0);
}

// ---------------- prep pass 1: W4 -> fp16 [N][K] ----------------
__global__ void __launch_bounds__(256)
dequant_w(const int* __restrict__ qw, const float* __restrict__ scl,
          const int* __restrict__ zro, _Float16* __restrict__ wh) {
  const unsigned int QTOT = (unsigned int)NDIM * KHALF;
  const unsigned int stride = gridDim.x * blockDim.x;
  for (unsigned int t = blockIdx.x * blockDim.x + threadIdx.x; t * 4u < QTOT;
       t += stride) {
    const unsigned int f = t * 4u;
    const unsigned int n = f >> 11;
    const unsigned int kk = f & (KHALF - 1);
    const unsigned int g = kk >> 6;
    const float s = scl[n * NGRP + g];
    const float fz = __uint_as_float(0x4B000000u | (unsigned int)zro[n * NGRP + g]);
    const i32x4 q = *(const i32x4*)(qw + f);
    u32x4 w;
#pragma unroll
    for (int e = 0; e < 4; ++e) w[e] = dq_pair(q[e], fz, s);
    *(u32x4*)(wh + (size_t)f * 2) = w;
  }
}

// ---------------- prep pass 2: x f32 -> fp16 (exact) ----------------
__global__ void __launch_bounds__(256)
cvt_x(const float* __restrict__ x, _Float16* __restrict__ xh) {
  const unsigned int XTOT = (unsigned int)MDIM * KDIM;
  const unsigned int stride = gridDim.x * blockDim.x;
  for (unsigned int t = blockIdx.x * blockDim.x + threadIdx.x; t * 8u < XTOT;
       t += stride) {
    const unsigned int f = t * 8u;
    const f32x4 a = *(const f32x4*)(x + f);
    const f32x4 b = *(const f32x4*)(x + f + 4);
    u32x4 w;
    w[0] = pk16(a[0], a[1]);
    w[1] = pk16(a[2], a[3]);
    w[2] = pk16(b[0], b[1]);
    w[3] = pk16(b[2], b[3]);
    *(u32x4*)(xh + f) = w;
  }
}

// ---------------- pass 3: fp16 GEMM, 256^2 8-phase ----------------
// LDS (fp16 elements): [buf:2][A=0/B=1][half:2][128 rows][64 k], chunk-XOR
// swizzled: row r, logical 16B-chunk c stored at c ^ (r&7). gload_lds dest
// is linear; the swizzle is pre-applied to the GLOBAL source column.
// Iteration i computes K-tiles t0=2i (buf0), t1=2i+1 (buf1):
//  ph1: rd a[0-3],b[0-1](buf0) | stage B0(t1)->buf1   | Q1 = a03 x b01
//  ph2: rd a[4-7]              | stage B1(t1)->buf1   | Q2 = a47 x b01
//  ph3: rd b[2-3]              | stage A0(t0+2)->buf0 | Q3 = a03 x b23
//  ph4:                        | stage A1(t0+2)->buf0 | Q4 = a47 x b23 | vmcnt(4)
//  ph5: rd a[0-3],b[0-1](buf1) | stage B0(t0+2)->buf0 | Q1'
//  ph6: rd a[4-7]              | stage B1(t0+2)->buf0 | Q2'
//  ph7: rd b[2-3]              | stage A0(t1+2)->buf1 | Q3'
//  ph8:                        | stage A1(t1+2)->buf1 | Q4' | vmcnt(4)
// Every stage lands after the barrier ending its region's last-read phase;
// every read is covered by a vmcnt(4)+barrier at most 2 phases earlier.
#define ABUF(b, h) ((b) * 32768 + (h) * 8192)
#define BBUF(b, h) ((b) * 32768 + 16384 + (h) * 8192)

#define BARRIER __builtin_amdgcn_s_barrier()
#define LGK0 do { asm volatile("s_waitcnt lgkmcnt(0)" ::: "memory"); \
                  __builtin_amdgcn_sched_barrier(0); } while (0)
#define VMC4 do { asm volatile("s_waitcnt vmcnt(4)" ::: "memory"); \
                  __builtin_amdgcn_sched_barrier(0); } while (0)

__global__ void __launch_bounds__(G_NTH, 2)
gemm_f16_8ph(const _Float16* __restrict__ xh, const _Float16* __restrict__ wh,
             const float* __restrict__ bia, float* __restrict__ outp) {
  __shared__ _Float16 lds[65536];  // 128 KiB

  const int tid = threadIdx.x;
  int wg = blockIdx.x;  // bijective XCD swizzle (688 = 8*86)
  wg = (wg & 7) * (G_NWG / 8) + (wg >> 3);
  const int by = wg / G_NTILN;
  const int bx = wg - by * G_NTILN;
  const int m0 = by * G_BM;
  const int n0 = bx * G_BN;

  // staging: per half-tile 1024 chunks of 16B; thread does chunks tid, tid+512
  const int rowL = tid >> 3;  // 0..63
  const int swc = (((tid & 7) ^ (rowL & 7)) << 3);  // pre-swizzled src col
  const unsigned int aO0 = (unsigned int)(m0 + rowL) * KDIM + swc;
  const unsigned int aO1 = aO0 + (unsigned int)128 * KDIM;
  const unsigned int bO0 = (unsigned int)(n0 + rowL) * KDIM + swc;
  const unsigned int bO1 = bO0 + (unsigned int)128 * KDIM;
  const int dst0 = tid << 3;  // fp16 elems; chunk tid+512 at +4096, src +64*K

#define ST(base_el, gb, thoff, ko)                                     \
  do {                                                                 \
    load_lds16((gb) + (thoff) + (ko), lds + (base_el) + dst0);         \
    load_lds16((gb) + (thoff) + (unsigned)64 * KDIM + (ko),            \
               lds + (base_el) + 4096 + dst0);                         \
  } while (0)

  // wave decomposition: 2M x 4N waves; per-wave C = 128x64
  const int wave = tid >> 6, lane = tid & 63;
  const int wm = wave >> 2, wn = wave & 3;
  const int fr = lane & 15, fq = lane >> 4;
  const int pc0 = (fq ^ (fr & 7)) << 3;        // ks=0 chunk (fp16 elems)
  const int pc1 = ((4 + fq) ^ (fr & 7)) << 3;  // ks=1 chunk
  const int aoff0 = fr * 64 + pc0, aoff1 = fr * 64 + pc1;
  const int bb = ((wn & 1) << 12) + fr * 64;
  const int boff0 = bb + pc0, boff1 = bb + pc1;

  const _Float16* aP0 = lds + ABUF(0, 0) + wm * 8192;
  const _Float16* aP1 = lds + ABUF(1, 0) + wm * 8192;
  const _Float16* bP0 = lds + BBUF(0, 0) + (wn >> 1) * 8192;
  const _Float16* bP1 = lds + BBUF(1, 0) + (wn >> 1) * 8192;

#define RD_A03(P)                                           \
  _Pragma("unroll") for (int u = 0; u < 4; ++u) {           \
    aF[u][0] = *(const f16x8*)((P) + u * 1024 + aoff0);     \
    aF[u][1] = *(const f16x8*)((P) + u * 1024 + aoff1);     \
  }
#define RD_A47(P)                                               \
  _Pragma("unroll") for (int u = 0; u < 4; ++u) {               \
    aF[4 + u][0] = *(const f16x8*)((P) + (4 + u) * 1024 + aoff0); \
    aF[4 + u][1] = *(const f16x8*)((P) + (4 + u) * 1024 + aoff1); \
  }
#define RD_B01(P)                                           \
  _Pragma("unroll") for (int v = 0; v < 2; ++v) {           \
    bF[v][0] = *(const f16x8*)((P) + v * 1024 + boff0);     \
    bF[v][1] = *(const f16x8*)((P) + v * 1024 + boff1);     \
  }
#define RD_B23(P)                                               \
  _Pragma("unroll") for (int v = 0; v < 2; ++v) {               \
    bF[2 + v][0] = *(const f16x8*)((P) + (2 + v) * 1024 + boff0); \
    bF[2 + v][1] = *(const f16x8*)((P) + (2 + v) * 1024 + boff1); \
  }
#define QUAD(MI, NI)                                                     \
  do {                                                                   \
    __builtin_amdgcn_s_setprio(1);                                       \
    _Pragma("unroll") for (int u = 0; u < 4; ++u) {                      \
      _Pragma("unroll") for (int v = 0; v < 2; ++v) {                    \
        acc[(MI) + u][(NI) + v] = __builtin_amdgcn_mfma_f32_16x16x32_f16( \
            aF[(MI) + u][0], bF[(NI) + v][0], acc[(MI) + u][(NI) + v], 0, 0, 0); \
        acc[(MI) + u][(NI) + v] = __builtin_amdgcn_mfma_f32_16x16x32_f16( \
            aF[(MI) + u][1], bF[(NI) + v][1], acc[(MI) + u][(NI) + v], 0, 0, 0); \
      }                                                                  \
    }                                                                    \
    __builtin_amdgcn_s_setprio(0);                                       \
  } while (0)

  f16x8 aF[8][2], bF[4][2];
  f32x4 acc[8][4];
  const f32x4 fzero = {0.f, 0.f, 0.f, 0.f};
#pragma unroll
  for (int i = 0; i < 8; ++i)
#pragma unroll
    for (int j = 0; j < 4; ++j) acc[i][j] = fzero;

  // prologue: bufA <- tile0 (A+B), bufB <- tile1 (A only; B staged in ph1/2)
  ST(ABUF(0, 0), xh, aO0, 0u);
  ST(ABUF(0, 1), xh, aO1, 0u);
  ST(BBUF(0, 0), wh, bO0, 0u);
  ST(BBUF(0, 1), wh, bO1, 0u);
  ST(ABUF(1, 0), xh, aO0, 64u);
  ST(ABUF(1, 1), xh, aO1, 64u);
  VMC4;  // first 8 loads (bufA) done; 4 (bufB.A) may remain in flight
  BARRIER;

  for (int it = 0; it < KDIM / 128; ++it) {
    const unsigned int k0 = (unsigned int)it << 7;
    const unsigned int ko1 = k0 + 64;              // tile t1 = 2i+1
    const unsigned int ko2 = (k0 + 128) & 4095u;   // tile t0+2 (wraps: unused)
    const unsigned int ko3 = (k0 + 192) & 4095u;   // tile t1+2

    // ph1
    RD_A03(aP0); RD_B01(bP0);
    ST(BBUF(1, 0), wh, bO0, ko1);
    BARRIER; LGK0; QUAD(0, 0); BARRIER;
    // ph2
    RD_A47(aP0);
    ST(BBUF(1, 1), wh, bO1, ko1);
    BARRIER; LGK0; QUAD(4, 0); BARRIER;
    // ph3
    RD_B23(bP0);
    ST(ABUF(0, 0), xh, aO0, ko2);
    BARRIER; LGK0; QUAD(0, 2); BARRIER;
    // ph4
    ST(ABUF(0, 1), xh, aO1, ko2);
    BARRIER; LGK0; QUAD(4, 2); VMC4; BARRIER;
    // ph5
    RD_A03(aP1); RD_B01(bP1);
    ST(BBUF(0, 0), wh, bO0, ko2);
    BARRIER; LGK0; QUAD(0, 0); BARRIER;
    // ph6
    RD_A47(aP1);
    ST(BBUF(0, 1), wh, bO1, ko2);
    BARRIER; LGK0; QUAD(4, 0); BARRIER;
    // ph7
    RD_B23(bP1);
    ST(ABUF(1, 0), xh, aO0, ko3);
    BARRIER; LGK0; QUAD(0, 2); BARRIER;
    // ph8
    ST(ABUF(1, 1), xh, aO1, ko3);
    BARRIER; LGK0; QUAD(4, 2); VMC4; BARRIER;
  }

  // epilogue: C/D col(n) = fr, row(m) = fq*4 + j
#pragma unroll
  for (int ni = 0; ni < 4; ++ni) {
    const int n = n0 + wn * 64 + ni * 16 + fr;
    const float bv = bia[n];
#pragma unroll
    for (int mi = 0; mi < 8; ++mi) {
      const int m = m0 + wm * 128 + mi * 16 + (fq << 2);
      const size_t base = (size_t)m * NDIM + n;
#pragma unroll
      for (int j = 0; j < 4; ++j)
        outp[base + (size_t)j * NDIM] = acc[mi][ni][j] + bv;
    }
  }
}

// ---------------- fallback: round-3 fused kernel (passes, 1170 us) --------
__global__ void __launch_bounds__(F_NTH)
wlinear_fused(const float* __restrict__ x, const int* __restrict__ qw,
              const float* __restrict__ scl, const int* __restrict__ zro,
              const float* __restrict__ bia, float* __restrict__ outp) {
  __shared__ _Float16 ldsA[F_BM][F_BK];
  __shared__ _Float16 ldsB[F_BN][F_BK];

  const int tid = threadIdx.x;
  int wg = blockIdx.x;
  wg = (wg & (NXCD - 1)) * (F_NWG / NXCD) + (wg >> 3);
  const int by = wg / F_NTILN;
  const int bx = wg - by * F_NTILN;
  const int m0 = by * F_BM;
  const int n0 = bx * F_BN;

  const int srow = tid >> 1;
  const int sh = tid & 1;
  const int ssw = srow & 7;
  const float* xrow = x + (size_t)(m0 + srow) * KDIM + sh * 32;
  const int* qrow = qw + (size_t)(n0 + srow) * KHALF + sh * 16;
  const float* sclrow = scl + (size_t)(n0 + srow) * NGRP;
  const int* zrow = zro + (size_t)(n0 + srow) * NGRP;

  const int wave = tid >> 6;
  const int lane = tid & 63;
  const int wr = wave >> 1;
  const int wc = wave & 1;
  const int fr = lane & 15;
  const int fq = lane >> 4;
  const int off0 = ((fq ^ (fr & 7)) << 3);

  const f32x4 fzero = {0.f, 0.f, 0.f, 0.f};
  f32x4 acc[4][4];
#pragma unroll
  for (int i = 0; i < 4; ++i)
#pragma unroll
    for (int j = 0; j < 4; ++j) acc[i][j] = fzero;

  f32x4 xv[8];
  i32x4 qv[4];
  {
    const f32x4* xp = (const f32x4*)xrow;
#pragma unroll
    for (int i = 0; i < 8; ++i) xv[i] = xp[i];
    const i32x4* qp = (const i32x4*)qrow;
#pragma unroll
    for (int i = 0; i < 4; ++i) qv[i] = qp[i];
  }
  float s_n = sclrow[0];
  float fz_n = __uint_as_float(0x4B000000u | (unsigned int)zrow[0]);

  for (int k0 = 0; k0 < KDIM; k0 += F_BK) {
    __syncthreads();
#pragma unroll
    for (int j = 0; j < 4; ++j) {
      u32x4 wch;
      wch[0] = pk16(xv[2 * j][0], xv[2 * j][1]);
      wch[1] = pk16(xv[2 * j][2], xv[2 * j][3]);
      wch[2] = pk16(xv[2 * j + 1][0], xv[2 * j + 1][1]);
      wch[3] = pk16(xv[2 * j + 1][2], xv[2 * j + 1][3]);
      const int ps = (sh * 4 + j) ^ ssw;
      *(u32x4*)&ldsA[srow][ps << 3] = wch;
    }
#pragma unroll
    for (int ii = 0; ii < 4; ++ii) {
      u32x4 wch;
#pragma unroll
      for (int e = 0; e < 4; ++e) wch[e] = dq_pair(qv[ii][e], fz_n, s_n);
      const int ps = (sh * 4 + ii) ^ ssw;
      *(u32x4*)&ldsB[srow][ps << 3] = wch;
    }
    if (k0 + F_BK < KDIM) {
      const f32x4* xp = (const f32x4*)(xrow + k0 + F_BK);
#pragma unroll
      for (int i = 0; i < 8; ++i) xv[i] = xp[i];
      const i32x4* qp = (const i32x4*)(qrow + ((k0 + F_BK) >> 1));
#pragma unroll
      for (int i = 0; i < 4; ++i) qv[i] = qp[i];
      const int gn = (k0 + F_BK) >> 7;
      s_n = sclrow[gn];
      fz_n = __uint_as_float(0x4B000000u | (unsigned int)zrow[gn]);
    }
    __syncthreads();

#pragma unroll
    for (int ks = 0; ks < F_BK; ks += 32) {
      const int off = (ks == 0) ? off0 : (off0 ^ 32);
      f16x8 a[4], b[4];
#pragma unroll
      for (int mi = 0; mi < 4; ++mi)
        a[mi] = *(const f16x8*)&ldsA[wr * 64 + mi * 16 + fr][off];
#pragma unroll
      for (int ni = 0; ni < 4; ++ni)
        b[ni] = *(const f16x8*)&ldsB[wc * 64 + ni * 16 + fr][off];
#pragma unroll
      for (int mi = 0; mi < 4; ++mi)
#pragma unroll
        for (int ni = 0; ni < 4; ++ni)
          acc[mi][ni] = __builtin_amdgcn_mfma_f32_16x16x32_f16(
              a[mi], b[ni], acc[mi][ni], 0, 0, 0);
    }
  }

#pragma unroll
  for (int ni = 0; ni < 4; ++ni) {
    const int n = n0 + wc * 64 + ni * 16 + fr;
    const float bv = bia[n];
#pragma unroll
    for (int mi = 0; mi < 4; ++mi) {
      const int m = m0 + wr * 64 + mi * 16 + (fq << 2);
      const size_t base = (size_t)m * NDIM + n;
#pragma unroll
      for (int j = 0; j < 4; ++j)
        outp[base + (size_t)j * NDIM] = acc[mi][ni][j] + bv;
    }
  }
}

extern "C" void kernel_launch(void* const* d_in, const int* in_sizes, int n_in,
                              void* d_out, int out_size, void* d_ws, size_t ws_size,
                              hipStream_t stream) {
  (void)in_sizes; (void)n_in; (void)out_size;
  const float* x = (const float*)d_in[0];
  const int* qw = (const int*)d_in[1];
  const float* scl = (const float*)d_in[2];
  const int* zro = (const int*)d_in[3];
  const float* bia = (const float*)d_in[4];
  float* outp = (float*)d_out;

  if (ws_size >= WS_NEED) {
    _Float16* wh = (_Float16*)d_ws;
    _Float16* xh = (_Float16*)((char*)d_ws + WBYTES);
    dequant_w<<<2048, 256, 0, stream>>>(qw, scl, zro, wh);
    cvt_x<<<1024, 256, 0, stream>>>(x, xh);
    gemm_f16_8ph<<<G_NWG, G_NTH, 0, stream>>>(xh, wh, bia, outp);
  } else {
    wlinear_fused<<<F_NWG, F_NTH, 0, stream>>>(x, qw, scl, zro, bia, outp);
  }
}